// Round 9
// baseline (224.813 us; speedup 1.0000x reference)
//
#include <hip/hip_runtime.h>

// Problem constants: S=128, D=512, H=8, W=64, NUM=16, SCALE=sqrt(8)
// All inputs and outputs fp32 (reference dtypes); fp32 compute throughout.
// Frozen empirical facts (r0-r8): XT[k][*] k-major transpose staging is the
// fast GEMM staging idiom; fused packaging (proj2 + scores in ONE dispatch)
// is worth ~25 us; scores occupancy is NOT the bottleneck (r4); nontemporal
// stores REGRESS (r6, partial-line RMW); wave-contiguous 1KB stores (r7) and
// proj4 at 2 blocks/CU (r8) are wins.
// This round's single variable: scores -> ONE WAVE PER (s,i) ROW. Removes
// both post-staging barriers + the cross-wave LDS reduction; waves desync
// so the 134 MB store stream spreads in time instead of a phase-locked
// terminal burst. Store geometry keeps r7's full-line 1KB wave stores.
#define INV_SCALE 0.35355339059327373f
#define LOG2E 1.4426950408889634f

struct Proj4Args {
  const float* x[4];
  const float* w[4];
  const float* b[4];
  float* y[4];
};

// ---------------------------------------------------------------------------
// Stage-1 projection GEMM, 512 blocks (r8 verbatim): blk = (p<<7)|(dt<<1)|sh.
// ---------------------------------------------------------------------------
__global__ __launch_bounds__(256) void proj4_kernel(Proj4Args A) {
  __shared__ float SH[6176];  // 4096 (WL 8x512) + 2080 (XT[32][65])
  const int blk = blockIdx.x;
  const int p = blk >> 7;
  const int dbase = ((blk >> 1) & 63) * 8;
  const int shalf = (blk & 1) * 64;
  const int t = threadIdx.x;
  const int s = t & 63;
  const int g = t >> 6;  // wave id; di pair = g*2 (wave-uniform)
  float* WL = SH;
  float(*XT)[65] = (float(*)[65])(SH + 4096);
  {
    const float4* wg = (const float4*)(A.w[p] + dbase * 512);
    float4* wl4 = (float4*)WL;
#pragma unroll
    for (int r = 0; r < 4; ++r) wl4[t + r * 256] = wg[t + r * 256];
  }
  const float* xg = A.x[p] + shalf * 512;  // this block's 64 rows
  const int row = t >> 3;  // 0..31; +32 covers rows 0..63
  const int col = t & 7;   // float4 column within the 32-k chunk
  float acc[2] = {0.f, 0.f};
  float4 pre[2];
#pragma unroll
  for (int r = 0; r < 2; ++r)
    pre[r] = ((const float4*)(xg + (row + r * 32) * 512))[col];  // chunk 0
  for (int c = 0; c < 16; ++c) {
    __syncthreads();  // also covers the W stage at c==0
#pragma unroll
    for (int r = 0; r < 2; ++r) {
      float4 f = pre[r];
      int rr = row + r * 32;
      XT[col * 4 + 0][rr] = f.x;
      XT[col * 4 + 1][rr] = f.y;
      XT[col * 4 + 2][rr] = f.z;
      XT[col * 4 + 3][rr] = f.w;
    }
    __syncthreads();
    if (c + 1 < 16) {
#pragma unroll
      for (int r = 0; r < 2; ++r)
        pre[r] = ((const float4*)(xg + (row + r * 32) * 512))[(c + 1) * 8 + col];
    }
#pragma unroll
    for (int k4 = 0; k4 < 8; ++k4) {
      float xv0 = XT[k4 * 4 + 0][s];
      float xv1 = XT[k4 * 4 + 1][s];
      float xv2 = XT[k4 * 4 + 2][s];
      float xv3 = XT[k4 * 4 + 3][s];
#pragma unroll
      for (int di = 0; di < 2; ++di) {
        // wave-uniform address -> LDS broadcast read (free)
        const float4 wv =
            *(const float4*)&WL[(g * 2 + di) * 512 + c * 32 + k4 * 4];
        acc[di] = fmaf(wv.x, xv0, acc[di]);
        acc[di] = fmaf(wv.y, xv1, acc[di]);
        acc[di] = fmaf(wv.z, xv2, acc[di]);
        acc[di] = fmaf(wv.w, xv3, acc[di]);
      }
    }
  }
  const float* bp = A.b[p] + dbase + g * 2;
  *(float2*)(A.y[p] + (shalf + s) * 512 + dbase + g * 2) =
      make_float2(acc[0] + bp[0], acc[1] + bp[1]);
}

// ---------------------------------------------------------------------------
// GEMM body for proj2 (CHUNK=16 instantiation, r7 verbatim).
// ---------------------------------------------------------------------------
template <int CHUNK>
__device__ __forceinline__ void gemm8_body(const float* xg, const float* wg_p,
                                           const float* bp, int dbase, int t,
                                           float* SH, float o[4]) {
  const int s = t & 127;
  const int h = t >> 7;
  float* WL = SH;                                // [8][512] = 4096 floats
  float(*XT)[129] = (float(*)[129])(SH + 4096);  // [CHUNK][129]
  {
    const float4* wg = (const float4*)(wg_p + dbase * 512);
    float4* wl4 = (float4*)WL;
#pragma unroll
    for (int r = 0; r < 4; ++r) wl4[t + r * 256] = wg[t + r * 256];
  }
  constexpr int C4 = CHUNK / 4;     // float4 cols per chunk row
  constexpr int RPT = C4 / 2;       // row-groups per thread
  constexpr int NCH = 512 / CHUNK;  // number of k chunks
  constexpr int RSTEP = 256 / C4;   // row stride between r-groups
  const int row = t / C4;
  const int col = t % C4;
  float acc[4] = {0.f, 0.f, 0.f, 0.f};
  float4 pre[RPT];
#pragma unroll
  for (int r = 0; r < RPT; ++r)
    pre[r] = ((const float4*)(xg + (row + r * RSTEP) * 512))[col];  // chunk 0
  for (int c = 0; c < NCH; ++c) {
    __syncthreads();  // also covers the W stage at c==0
#pragma unroll
    for (int r = 0; r < RPT; ++r) {
      float4 f = pre[r];
      int rr = row + r * RSTEP;
      XT[col * 4 + 0][rr] = f.x;
      XT[col * 4 + 1][rr] = f.y;
      XT[col * 4 + 2][rr] = f.z;
      XT[col * 4 + 3][rr] = f.w;
    }
    __syncthreads();
    if (c + 1 < NCH) {
#pragma unroll
      for (int r = 0; r < RPT; ++r)
        pre[r] =
            ((const float4*)(xg + (row + r * RSTEP) * 512))[(c + 1) * C4 + col];
    }
#pragma unroll
    for (int k4 = 0; k4 < C4; ++k4) {
      float xv0 = XT[k4 * 4 + 0][s];
      float xv1 = XT[k4 * 4 + 1][s];
      float xv2 = XT[k4 * 4 + 2][s];
      float xv3 = XT[k4 * 4 + 3][s];
#pragma unroll
      for (int di = 0; di < 4; ++di) {
        // wave-uniform address -> LDS broadcast read (free)
        const float4 wv =
            *(const float4*)&WL[(h * 4 + di) * 512 + c * CHUNK + k4 * 4];
        acc[di] = fmaf(wv.x, xv0, acc[di]);
        acc[di] = fmaf(wv.y, xv1, acc[di]);
        acc[di] = fmaf(wv.z, xv2, acc[di]);
        acc[di] = fmaf(wv.w, xv3, acc[di]);
      }
    }
  }
#pragma unroll
  for (int di = 0; di < 4; ++di) o[di] = acc[di] + bp[dbase + h * 4 + di];
}

// ---------------------------------------------------------------------------
// Fused second launch.
//   blocks 0..255      -> stage-2 projection + DIRECT final-output epilogue
//   blocks 256..2303   -> scores (softmax att), needs stage-1 only
// ---------------------------------------------------------------------------
struct FusedArgs {
  const float* w2[4];  // Wvo,Wqo,Wao,Wko
  const float* b2[4];
  const float* vp;
  const float* qp;
  const float* ap;
  const float* kp;
  float* out;
};

__device__ __forceinline__ void proj2_direct_body(const FusedArgs& F, int blk,
                                                  int t, float* SH) {
  const int p = blk >> 6;
  const int dbase = (blk & 63) * 8;
  const float* xsrc[4] = {F.vp, F.qp, F.ap, F.kp};
  float o[4];
  gemm8_body<16>(xsrc[p], F.w2[p], F.b2[p], dbase, t, SH, o);
  const int s = t & 127;
  const int h = t >> 7;
  const int c_head = dbase >> 6;        // head index of this d-tile
  const int i0 = (dbase & 63) + h * 4;  // within-head coordinate base
  if (p == 3) {
    // k_res at flat offset 196608: [s, w*8 + head]
#pragma unroll
    for (int di = 0; di < 4; ++di)
      F.out[196608 + s * 512 + (i0 + di) * 8 + c_head] = o[di];
    return;  // p is block-uniform: no divergent-barrier hazard
  }
  const float* fac = (p == 0) ? F.vp : (p == 1) ? F.qp : F.kp;
  const float* S0 = (p == 0) ? F.qp : F.vp;
  const float* S1 = (p == 2) ? F.qp : F.kp;
  __syncthreads();  // all GEMM LDS reads done; reuse SH
  float* Sm = SH;   // [2][128][8] = 2048 floats
#pragma unroll
  for (int m = 0; m < 2; ++m) {
    const float* M = m ? S1 : S0;
#pragma unroll
    for (int cc = 0; cc < 4; ++cc) {
      const int c = h * 4 + cc;
      const float4* r4 = (const float4*)(M + s * 512 + c * 64);
      float sum = 0.f;
#pragma unroll
      for (int u = 0; u < 16; ++u) {
        float4 f = r4[u];
        sum += (f.x + f.y) + (f.z + f.w);
      }
      Sm[m * 1024 + s * 8 + c] = sum;
    }
  }
  __syncthreads();
  float prod[8];
#pragma unroll
  for (int c = 0; c < 8; ++c)
    prod[c] = Sm[s * 8 + c] * Sm[1024 + s * 8 + c];
#pragma unroll
  for (int di = 0; di < 4; ++di) {
    const int i = i0 + di;
    float A1 = 0.f;
#pragma unroll
    for (int c = 0; c < 8; ++c)
      A1 = fmaf(fac[s * 512 + c * 64 + i], prod[c], A1);
    // {v,q,a}_res at flat offset p*65536: [i, s*8 + head]
    F.out[p * 65536 + i * 1024 + s * 8 + c_head] = o[di] * (A1 * INV_SCALE);
  }
}

// scores body — WAVE-PER-ROW: block = (s, i0..i0+3); wave wid owns row
// i = i0+wid. Lane ln holds, for k=0..15, the float4 at flat value index
// k*256 + ln*4 (j = 4k + (ln>>4), l = 4*(ln&15)+e). All 16 stores are
// fully wave-contiguous 1KB (r7's proven geometry). Softmax denominator is
// a pure in-wave shfl_xor reduce: NO barrier after staging, no LDS
// round-trip — waves desync and spread the store stream in time.
// No max-subtraction (logits sigma~1, max << 88, fp32 exp can't overflow);
// log2e folded into u[] so exp2f.
// LDS reads: tq scalar = 16-way broadcast groups (conflict-free); ta b128 =
// 16 distinct float4 + 4-way broadcast = 2 lanes/bank (free per m136).
__device__ __forceinline__ void scores_body(const float* __restrict__ vp,
                                            const float* __restrict__ qp,
                                            const float* __restrict__ ap,
                                            float* __restrict__ out, int b,
                                            int t, float* SH) {
  const int s = b >> 4;
  const int i0 = (b & 15) * 4;
  float* tqL = SH;
  float* taL = SH + 512;
  if (t < 128)
    ((float4*)tqL)[t] = ((const float4*)(qp + s * 512))[t];
  else
    ((float4*)taL)[t - 128] = ((const float4*)(ap + s * 512))[t - 128];
  const int wid = t >> 6, ln = t & 63;
  const int i = i0 + wid;  // this wave's row
  // u[c]: wave-uniform broadcast global loads (L2-hot), issued pre-barrier
  const float* vrow = vp + s * 512 + i;
  float u[8];
#pragma unroll
  for (int c = 0; c < 8; ++c) u[c] = vrow[c * 64] * (INV_SCALE * LOG2E);
  __syncthreads();  // staging visible; the ONLY barrier in this body
  const int jb = ln >> 4;        // j offset within each 4k group
  const int lq = (ln & 15) * 4;  // l base (4 consecutive l)
  float4 acc[16];
#pragma unroll
  for (int k = 0; k < 16; ++k) acc[k] = make_float4(0.f, 0.f, 0.f, 0.f);
#pragma unroll
  for (int c = 0; c < 8; ++c) {
    const float4 ta4 = *reinterpret_cast<const float4*>(&taL[c * 64 + lq]);
    const float* tq_c = &tqL[c * 64 + jb];
    const float uc = u[c];
#pragma unroll
    for (int k = 0; k < 16; ++k) {
      float m = uc * tq_c[4 * k];
      acc[k].x = fmaf(m, ta4.x, acc[k].x);
      acc[k].y = fmaf(m, ta4.y, acc[k].y);
      acc[k].z = fmaf(m, ta4.z, acc[k].z);
      acc[k].w = fmaf(m, ta4.w, acc[k].w);
    }
  }
  float sl = 0.f;
#pragma unroll
  for (int k = 0; k < 16; ++k) {
    acc[k].x = exp2f(acc[k].x);
    acc[k].y = exp2f(acc[k].y);
    acc[k].z = exp2f(acc[k].z);
    acc[k].w = exp2f(acc[k].w);
    sl += (acc[k].x + acc[k].y) + (acc[k].z + acc[k].w);
  }
#pragma unroll
  for (int o = 32; o; o >>= 1) sl += __shfl_xor(sl, o);
  const float sc = 1.0f / sl;
  // 16 stores, each wave-contiguous 1KB: float4 at base + k*256 + ln*4
  float* ob = out + 262144L + (long)s * 262144 + (long)i * 4096 + ln * 4;
#pragma unroll
  for (int k = 0; k < 16; ++k) {
    *reinterpret_cast<float4*>(ob + k * 256) =
        make_float4(acc[k].x * sc, acc[k].y * sc, acc[k].z * sc, acc[k].w * sc);
  }
}

__global__ __launch_bounds__(256) void fused_kernel(FusedArgs F) {
  __shared__ float SH[6160];  // 4096 (WL) + 16*129 (XT); scores uses 1024
  const int b = blockIdx.x;
  if (b < 256)
    proj2_direct_body(F, b, threadIdx.x, SH);
  else
    scores_body(F.vp, F.qp, F.ap, F.out, b - 256, threadIdx.x, SH);
}

extern "C" void kernel_launch(void* const* d_in, const int* in_sizes, int n_in,
                              void* d_out, int out_size, void* d_ws, size_t ws_size,
                              hipStream_t stream) {
  // setup_inputs order: v,q,a,k, 4 masks (unused), then Wv,bv,Wq,bq,Wa,ba,Wk,bk,
  //                     Wvo,bvo,Wqo,bqo,Wao,bao,Wko,bko
  int wb = 8;
  if (n_in >= 5 && in_sizes[4] == 262144) wb = 4;  // defensive: masks absent
  const float* W[8];
  const float* B[8];
  for (int i = 0; i < 8; ++i) {
    W[i] = (const float*)d_in[wb + 2 * i];
    B[i] = (const float*)d_in[wb + 2 * i + 1];
  }
  float* ws = (float*)d_ws;
  float* vp = ws;
  float* qp = ws + 65536;
  float* ap = ws + 131072;
  float* kp = ws + 196608;
  float* out = (float*)d_out;

  // Stage 1: input projections (vp = v@Wv^T+bv, etc.) — 512 blocks, 2/CU
  Proj4Args a1;
  for (int i = 0; i < 4; ++i) {
    a1.x[i] = (const float*)d_in[i];
    a1.w[i] = W[i];
    a1.b[i] = B[i];
  }
  a1.y[0] = vp; a1.y[1] = qp; a1.y[2] = ap; a1.y[3] = kp;
  hipLaunchKernelGGL(proj4_kernel, dim3(512), dim3(256), 0, stream, a1);

  // Fused: stage-2 projections w/ direct final outputs (256) + scores (2048)
  FusedArgs F;
  for (int i = 0; i < 4; ++i) {
    F.w2[i] = W[4 + i];
    F.b2[i] = B[4 + i];
  }
  F.vp = vp; F.qp = qp; F.ap = ap; F.kp = kp; F.out = out;
  hipLaunchKernelGGL(fused_kernel, dim3(2304), dim3(256), 0, stream, F);
}